// Round 9
// baseline (1009.622 us; speedup 1.0000x reference)
//
#include <hip/hip_runtime.h>
#include <hip/hip_bf16.h>
#include <hip/hip_fp16.h>

#define N_NODES 50000
#define N_EDGES 800000
constexpr float BN_EPS = 1e-5f;
constexpr int NCHUNK = (N_NODES + 1023) / 1024;   // 49

typedef unsigned short ushortT;
typedef float fx4 __attribute__((ext_vector_type(4)));

__device__ __forceinline__ unsigned short f2bf(float f) {
    __hip_bfloat16 h = __float2bfloat16(f);   // RNE
    return __builtin_bit_cast(unsigned short, h);
}
// uint2 = 4 packed bf16 -> 4 floats
__device__ __forceinline__ void cvt4(uint2 v, float* f) {
    f[0] = __uint_as_float(v.x << 16); f[1] = __uint_as_float(v.x & 0xffff0000u);
    f[2] = __uint_as_float(v.y << 16); f[3] = __uint_as_float(v.y & 0xffff0000u);
}
__device__ __forceinline__ float dec_w(unsigned rec) {
    return __half2float(__builtin_bit_cast(__half, (unsigned short)(rec >> 16)));
}

// ---------------- degree / CSR build ----------------

__global__ void count_deg(const int* __restrict__ dst, int* cnts) {
    int e = blockIdx.x * 256 + threadIdx.x;
    if (e < N_EDGES) atomicAdd(&cnts[dst[e]], 1);
}

__global__ void finalize_deg(const int* __restrict__ cnts, float* __restrict__ dinv) {
    int i = blockIdx.x * 256 + threadIdx.x;
    if (i < N_NODES) dinv[i] = rsqrtf((float)cnts[i] + 1.0f);
}

// scan over (counts[i]+1): offs[0..N], last entry = E+N
__global__ __launch_bounds__(256)
void scan_block_sums(const int* __restrict__ counts, int* __restrict__ totals) {
    __shared__ int red[4];
    int tid = threadIdx.x;
    int base = blockIdx.x * 1024 + tid * 4;
    int s = 0;
    #pragma unroll
    for (int j = 0; j < 4; ++j) { int i = base + j; if (i < N_NODES) s += counts[i] + 1; }
    #pragma unroll
    for (int d = 1; d < 64; d <<= 1) s += __shfl_xor(s, d, 64);
    if ((tid & 63) == 0) red[tid >> 6] = s;
    __syncthreads();
    if (tid == 0) totals[blockIdx.x] = red[0] + red[1] + red[2] + red[3];
}

__global__ __launch_bounds__(256)
void scan_write(const int* __restrict__ counts, const int* __restrict__ totals,
                int* __restrict__ offs, int* __restrict__ cursor) {
    __shared__ int chunkbase;
    __shared__ int wsum[4];
    int tid = threadIdx.x, lane = tid & 63, wid = tid >> 6;
    if (tid == 0) { int a = 0; for (int i = 0; i < (int)blockIdx.x; ++i) a += totals[i]; chunkbase = a; }
    int base = blockIdx.x * 1024 + tid * 4;
    int v[4]; int s = 0;
    #pragma unroll
    for (int j = 0; j < 4; ++j) { int i = base + j; v[j] = (i < N_NODES) ? counts[i] + 1 : 0; s += v[j]; }
    int ts = s;
    #pragma unroll
    for (int d = 1; d < 64; d <<= 1) { int t = __shfl_up(ts, d, 64); if (lane >= d) ts += t; }
    if (lane == 63) wsum[wid] = ts;
    __syncthreads();
    int wbase = 0;
    #pragma unroll
    for (int w = 0; w < 4; ++w) if (w < wid) wbase += wsum[w];
    int excl = chunkbase + wbase + (ts - s);
    #pragma unroll
    for (int j = 0; j < 4; ++j) {
        int i = base + j;
        if (i < N_NODES) { offs[i] = excl; cursor[i] = excl; }
        excl += v[j];
        if (i == N_NODES - 1) offs[N_NODES] = excl;
    }
}

// compressed edge record: u16 src | f16 norm << 16
__global__ void fill_csr(const int* __restrict__ src, const int* __restrict__ dst,
                         const float* __restrict__ dinv, int* cursor,
                         unsigned* __restrict__ edges) {
    int e = blockIdx.x * 256 + threadIdx.x;
    if (e < N_EDGES) {
        int s = src[e], d = dst[e];
        int pos = atomicAdd(&cursor[d], 1);
        unsigned short hb = __builtin_bit_cast(unsigned short, __float2half(dinv[s] * dinv[d]));
        edges[pos] = (unsigned)s | ((unsigned)hb << 16);
    }
}

// self edge (weight 1/deg) appended in each row's last slot
__global__ void fill_self(const int* __restrict__ counts, const int* __restrict__ offs,
                          unsigned* __restrict__ edges) {
    int i = blockIdx.x * 256 + threadIdx.x;
    if (i < N_NODES) {
        float w = 1.0f / ((float)counts[i] + 1.0f);
        unsigned short hb = __builtin_bit_cast(unsigned short, __float2half(w));
        edges[offs[i] + counts[i]] = (unsigned)i | ((unsigned)hb << 16);
    }
}

// ---------------- GEMM: H(bf16, feature-sliced) = bn_relu(X) @ W ----------------
// H layout: [slab][N_NODES][32] bf16, slab = feature/32.  X stays [N][FI] f32.

template<int FI, int FO, bool BN, bool RELU>
__global__ __launch_bounds__(256)
void gemm_bn(const float* __restrict__ X, const float* __restrict__ W,
             ushortT* __restrict__ Hb, const float* __restrict__ stats_prev,
             const float* __restrict__ g_prev, const float* __restrict__ be_prev) {
    constexpr int CT = FO / 4;        // col-threads
    constexpr int RT = 256 / CT;      // row-threads
    constexpr int ROWS = RT * 4;      // rows per tile
    __shared__ ushortT Ws[FI * FO];   // bf16 weights
    __shared__ float xs[ROWS * FI];
    __shared__ float sscale[FI], sshift[FI];
    if constexpr (BN) {
        if (threadIdx.x < FI) {
            constexpr float invN = 1.0f / (float)N_NODES;
            int k = threadIdx.x;
            float m = stats_prev[k] * invN;
            float var = stats_prev[FI + k] * invN - m * m;
            float is = rsqrtf(var + BN_EPS) * g_prev[k];
            sscale[k] = is;
            sshift[k] = be_prev[k] - m * is;
        }
    }
    for (int i = threadIdx.x * 8; i < FI * FO; i += 256 * 8) {
        float4 w0 = *(const float4*)&W[i];
        float4 w1 = *(const float4*)&W[i + 4];
        ushortT us[8] = { f2bf(w0.x), f2bf(w0.y), f2bf(w0.z), f2bf(w0.w),
                          f2bf(w1.x), f2bf(w1.y), f2bf(w1.z), f2bf(w1.w) };
        *(uint4*)&Ws[i] = *(uint4*)us;
    }
    const int ct = threadIdx.x % CT, rt = threadIdx.x / CT;
    const int col = ct * 4;
    ushortT* Hcol = Hb + (size_t)(col >> 5) * N_NODES * 32 + (col & 31);
    const int ntiles = (N_NODES + ROWS - 1) / ROWS;
    for (int tile = blockIdx.x; tile < ntiles; tile += gridDim.x) {
        const int base = tile * ROWS;
        __syncthreads();
        for (int t = threadIdx.x; t < ROWS * FI / 4; t += 256) {
            int r = t / (FI / 4), k4 = (t % (FI / 4)) * 4;
            int gr = base + r;
            float4 v = (gr < N_NODES) ? *(const float4*)&X[(size_t)gr * FI + k4]
                                      : make_float4(0.f, 0.f, 0.f, 0.f);
            if constexpr (BN) {
                float4 sc = *(const float4*)&sscale[k4];
                float4 sh = *(const float4*)&sshift[k4];
                v.x = fmaf(v.x, sc.x, sh.x); v.y = fmaf(v.y, sc.y, sh.y);
                v.z = fmaf(v.z, sc.z, sh.z); v.w = fmaf(v.w, sc.w, sh.w);
                if constexpr (RELU) {
                    v.x = fmaxf(v.x, 0.f); v.y = fmaxf(v.y, 0.f);
                    v.z = fmaxf(v.z, 0.f); v.w = fmaxf(v.w, 0.f);
                }
            }
            *(float4*)&xs[r * FI + k4] = v;
        }
        __syncthreads();
        float acc[4][4] = {};
        #pragma unroll 2
        for (int k4 = 0; k4 < FI; k4 += 4) {
            float4 xv[4], wv[4];
            #pragma unroll
            for (int ri = 0; ri < 4; ++ri)
                xv[ri] = *(const float4*)&xs[(rt * 4 + ri) * FI + k4];
            #pragma unroll
            for (int j = 0; j < 4; ++j) {
                ushort4 wu = *(const ushort4*)&Ws[(k4 + j) * FO + col];
                wv[j] = make_float4(__uint_as_float((unsigned)wu.x << 16),
                                    __uint_as_float((unsigned)wu.y << 16),
                                    __uint_as_float((unsigned)wu.z << 16),
                                    __uint_as_float((unsigned)wu.w << 16));
            }
            #pragma unroll
            for (int ri = 0; ri < 4; ++ri) {
                #pragma unroll
                for (int j = 0; j < 4; ++j) {
                    float xk = ((const float*)&xv[ri])[j];
                    acc[ri][0] = fmaf(xk, wv[j].x, acc[ri][0]);
                    acc[ri][1] = fmaf(xk, wv[j].y, acc[ri][1]);
                    acc[ri][2] = fmaf(xk, wv[j].z, acc[ri][2]);
                    acc[ri][3] = fmaf(xk, wv[j].w, acc[ri][3]);
                }
            }
        }
        #pragma unroll
        for (int ri = 0; ri < 4; ++ri) {
            int row = base + rt * 4 + ri;
            if (row < N_NODES) {
                ushortT us[4] = { f2bf(acc[ri][0]), f2bf(acc[ri][1]),
                                  f2bf(acc[ri][2]), f2bf(acc[ri][3]) };
                *(ushort4*)&Hcol[(size_t)row * 32] = *(ushort4*)us;
            }
        }
    }
}

// ---------------- sliced aggregation, TRUE XCD pinning ----------------
// pass = (real XCC_ID) % NPASS: every block gathering slab p runs on an XCD whose L2
// holds ONLY slab p (3.2 MB < 4 MiB). Rows claimed via per-pass atomic cursor in
// 128-row batches (runtime pass => static partition impossible). Streaming accesses
// (edges/offs) stay L2-cached; out-writes are non-temporal.

template<int FO>
__global__ __launch_bounds__(256)
void aggregate_sliced(const ushortT* __restrict__ Hb, const int* __restrict__ offs,
                      const unsigned* __restrict__ edges, const float* __restrict__ bias,
                      float* __restrict__ out, float* __restrict__ stats,
                      int* __restrict__ cursor) {
    constexpr int NPASS = FO / 32;          // 4 (FO=128) or 2 (FO=64)
    int xcc;
    asm("s_getreg_b32 %0, hwreg(HW_REG_XCC_ID)" : "=s"(xcc));
    const int pass = xcc & (NPASS - 1);
    const int lt = threadIdx.x & 7;         // 8 lanes per row, 4 feats (8 B) each
    const int sub = threadIdx.x >> 3;       // 32 rows per iter, 4 iters per claim
    const uint2* S2 = (const uint2*)(Hb + (size_t)pass * N_NODES * 32);
    const int f0 = pass * 32 + lt * 4;
    const float4 b4 = *(const float4*)&bias[f0];
    float s[4] = {}, s2[4] = {};
    __shared__ int batch_s;
    for (;;) {
        __syncthreads();
        if (threadIdx.x == 0) batch_s = atomicAdd(cursor + pass, 128);
        __syncthreads();
        const int batch = batch_s;
        if (batch >= N_NODES) break;
        #pragma unroll
        for (int it = 0; it < 4; ++it) {
            int r = batch + it * 32 + sub;
            if (r >= N_NODES) break;
            float a[4] = { b4.x, b4.y, b4.z, b4.w };
            int e = offs[r], en = offs[r + 1];
            for (; e + 2 <= en; e += 2) {
                uint2 ee = *(const uint2*)&edges[e];
                uint2 v0 = S2[(size_t)(ee.x & 0xffff) * 8 + lt];
                uint2 v1 = S2[(size_t)(ee.y & 0xffff) * 8 + lt];
                float w0 = dec_w(ee.x), w1 = dec_w(ee.y);
                float g0[4], g1[4];
                cvt4(v0, g0); cvt4(v1, g1);
                #pragma unroll
                for (int j = 0; j < 4; ++j) a[j] = fmaf(g0[j], w0, a[j]);
                #pragma unroll
                for (int j = 0; j < 4; ++j) a[j] = fmaf(g1[j], w1, a[j]);
            }
            if (e < en) {
                unsigned ee = edges[e];
                float w = dec_w(ee);
                float g[4];
                cvt4(S2[(size_t)(ee & 0xffff) * 8 + lt], g);
                #pragma unroll
                for (int j = 0; j < 4; ++j) a[j] = fmaf(g[j], w, a[j]);
            }
            fx4 o4 = { a[0], a[1], a[2], a[3] };
            __builtin_nontemporal_store(o4, (fx4*)&out[(size_t)r * FO + f0]);
            #pragma unroll
            for (int j = 0; j < 4; ++j) { s[j] += a[j]; s2[j] += a[j] * a[j]; }
        }
    }
    __shared__ float ls[256][4], ls2[256][4];
    #pragma unroll
    for (int j = 0; j < 4; ++j) { ls[threadIdx.x][j] = s[j]; ls2[threadIdx.x][j] = s2[j]; }
    __syncthreads();
    if (sub == 0) {
        for (int t = 1; t < 32; ++t) {
            #pragma unroll
            for (int j = 0; j < 4; ++j) {
                s[j] += ls[t * 8 + lt][j];
                s2[j] += ls2[t * 8 + lt][j];
            }
        }
        #pragma unroll
        for (int j = 0; j < 4; ++j) {
            atomicAdd(&stats[f0 + j], s[j]);
            atomicAdd(&stats[FO + f0 + j], s2[j]);
        }
    }
}

// ---------------- final BatchNorm normalize (layer 5 only) ----------------

template<int FO, bool RELU>
__global__ __launch_bounds__(256)
void bn_norm(const float* __restrict__ X, const float* __restrict__ stats,
             const float* __restrict__ g, const float* __restrict__ be,
             float* __restrict__ Y) {
    constexpr float invN = 1.0f / (float)N_NODES;
    const int total4 = N_NODES * FO / 4;
    for (int idx = blockIdx.x * 256 + threadIdx.x; idx < total4; idx += gridDim.x * 256) {
        int o4 = (idx * 4) & (FO - 1);
        float4 x = ((const float4*)X)[idx];
        float y[4];
        #pragma unroll
        for (int j = 0; j < 4; ++j) {
            int o = o4 + j;
            float m = stats[o] * invN;
            float v = stats[FO + o] * invN - m * m;
            float istd = rsqrtf(v + BN_EPS);
            float val = ((&x.x)[j] - m) * istd * g[o] + be[o];
            if (RELU) val = fmaxf(val, 0.f);
            y[j] = val;
        }
        ((float4*)Y)[idx] = make_float4(y[0], y[1], y[2], y[3]);
    }
}

// ---------------- driver ----------------

extern "C" void kernel_launch(void* const* d_in, const int* in_sizes, int n_in,
                              void* d_out, int out_size, void* d_ws, size_t ws_size,
                              hipStream_t stream) {
    const float* x  = (const float*)d_in[0];
    const int* ei   = (const int*)d_in[1];
    const int* src  = ei;
    const int* dst  = ei + N_EDGES;

    size_t off = 0;
    auto alloc = [&](size_t bytes) -> void* {
        void* p = (char*)d_ws + off;
        off += (bytes + 255) & ~(size_t)255;
        return p;
    };
    int*      counts = (int*)     alloc((size_t)N_NODES * 4);
    int*      offs   = (int*)     alloc((size_t)(N_NODES + 1) * 4);
    int*      cursor = (int*)     alloc((size_t)N_NODES * 4);
    int*      totals = (int*)     alloc((size_t)NCHUNK * 4);
    float*    dinv   = (float*)   alloc((size_t)N_NODES * 4);
    unsigned* edges  = (unsigned*)alloc((size_t)(N_EDGES + N_NODES) * 4);
    float*    stats  = (float*)   alloc(6 * 256 * 4);
    int*      wcurs  = (int*)     alloc(64 * 4);             // 6 layers x 8 pass-cursors
    ushortT*  Hb     = (ushortT*) alloc((size_t)N_NODES * 128 * 2);
    float*    A0     = (float*)   alloc((size_t)N_NODES * 128 * 4);
    float*    A1     = (float*)   alloc((size_t)N_NODES * 128 * 4);

    (void)hipMemsetAsync(counts, 0, (size_t)N_NODES * 4, stream);
    (void)hipMemsetAsync(stats, 0, 6 * 256 * 4, stream);
    (void)hipMemsetAsync(wcurs, 0, 64 * 4, stream);

    count_deg<<<(N_EDGES + 255) / 256, 256, 0, stream>>>(dst, counts);
    finalize_deg<<<(N_NODES + 255) / 256, 256, 0, stream>>>(counts, dinv);
    scan_block_sums<<<NCHUNK, 256, 0, stream>>>(counts, totals);
    scan_write<<<NCHUNK, 256, 0, stream>>>(counts, totals, offs, cursor);
    fill_csr<<<(N_EDGES + 255) / 256, 256, 0, stream>>>(src, dst, dinv, cursor, edges);
    fill_self<<<(N_NODES + 255) / 256, 256, 0, stream>>>(counts, offs, edges);

    const float* W[6]; const float* b[6]; const float* g[6]; const float* be[6];
    for (int j = 0; j < 6; ++j) {
        W[j]  = (const float*)d_in[2 + 4 * j];
        b[j]  = (const float*)d_in[3 + 4 * j];
        g[j]  = (const float*)d_in[4 + 4 * j];
        be[j] = (const float*)d_in[5 + 4 * j];
    }
    float* st[6];
    for (int j = 0; j < 6; ++j) st[j] = stats + j * 256;
    float* dout = (float*)d_out;

    gemm_bn<128, 128, false, false><<<768, 256, 0, stream>>>(x, W[0], Hb, nullptr, nullptr, nullptr);
    aggregate_sliced<128><<<2048, 256, 0, stream>>>(Hb, offs, edges, b[0], A0, st[0], wcurs + 0);

    gemm_bn<128, 128, true, true><<<768, 256, 0, stream>>>(A0, W[1], Hb, st[0], g[0], be[0]);
    aggregate_sliced<128><<<2048, 256, 0, stream>>>(Hb, offs, edges, b[1], A1, st[1], wcurs + 8);

    gemm_bn<128, 64, true, true><<<768, 256, 0, stream>>>(A1, W[2], Hb, st[1], g[1], be[1]);
    aggregate_sliced<64><<<2048, 256, 0, stream>>>(Hb, offs, edges, b[2], A0, st[2], wcurs + 16);

    gemm_bn<64, 128, true, false><<<768, 256, 0, stream>>>(A0, W[3], Hb, st[2], g[2], be[2]);
    aggregate_sliced<128><<<2048, 256, 0, stream>>>(Hb, offs, edges, b[3], A1, st[3], wcurs + 24);

    gemm_bn<128, 128, true, true><<<768, 256, 0, stream>>>(A1, W[4], Hb, st[3], g[3], be[3]);
    aggregate_sliced<128><<<2048, 256, 0, stream>>>(Hb, offs, edges, b[4], A0, st[4], wcurs + 32);

    gemm_bn<128, 128, true, true><<<768, 256, 0, stream>>>(A0, W[5], Hb, st[4], g[4], be[4]);
    aggregate_sliced<128><<<2048, 256, 0, stream>>>(Hb, offs, edges, b[5], dout, st[5], wcurs + 40);
    bn_norm<128, false><<<2048, 256, 0, stream>>>(dout, st[5], g[5], be[5], dout);
}

// Round 11
// 833.961 us; speedup vs baseline: 1.2106x; 1.2106x over previous
//
#include <hip/hip_runtime.h>
#include <hip/hip_bf16.h>
#include <hip/hip_fp16.h>

#define N_NODES 50000
#define N_EDGES 800000
constexpr float BN_EPS = 1e-5f;
constexpr int NCHUNK = (N_NODES + 1023) / 1024;   // 49
constexpr int NTILES = (N_NODES + 63) / 64;       // 782

typedef unsigned short ushortT;
typedef float fx4 __attribute__((ext_vector_type(4)));
typedef short bf16x8 __attribute__((ext_vector_type(8)));

__device__ __forceinline__ unsigned short f2bf(float f) {
    __hip_bfloat16 h = __float2bfloat16(f);   // RNE
    return __builtin_bit_cast(unsigned short, h);
}
// uint2 = 4 packed bf16 -> 4 floats
__device__ __forceinline__ void cvt4(uint2 v, float* f) {
    f[0] = __uint_as_float(v.x << 16); f[1] = __uint_as_float(v.x & 0xffff0000u);
    f[2] = __uint_as_float(v.y << 16); f[3] = __uint_as_float(v.y & 0xffff0000u);
}
__device__ __forceinline__ float dec_w(unsigned rec) {
    return __half2float(__builtin_bit_cast(__half, (unsigned short)(rec >> 16)));
}

// ---------------- degree / CSR build ----------------

__global__ void count_deg(const int* __restrict__ dst, int* cnts) {
    int e = blockIdx.x * 256 + threadIdx.x;
    if (e < N_EDGES) atomicAdd(&cnts[dst[e]], 1);
}

__global__ void finalize_deg(const int* __restrict__ cnts, float* __restrict__ dinv) {
    int i = blockIdx.x * 256 + threadIdx.x;
    if (i < N_NODES) dinv[i] = rsqrtf((float)cnts[i] + 1.0f);
}

// scan over (counts[i]+1): offs[0..N], last entry = E+N
__global__ __launch_bounds__(256)
void scan_block_sums(const int* __restrict__ counts, int* __restrict__ totals) {
    __shared__ int red[4];
    int tid = threadIdx.x;
    int base = blockIdx.x * 1024 + tid * 4;
    int s = 0;
    #pragma unroll
    for (int j = 0; j < 4; ++j) { int i = base + j; if (i < N_NODES) s += counts[i] + 1; }
    #pragma unroll
    for (int d = 1; d < 64; d <<= 1) s += __shfl_xor(s, d, 64);
    if ((tid & 63) == 0) red[tid >> 6] = s;
    __syncthreads();
    if (tid == 0) totals[blockIdx.x] = red[0] + red[1] + red[2] + red[3];
}

__global__ __launch_bounds__(256)
void scan_write(const int* __restrict__ counts, const int* __restrict__ totals,
                int* __restrict__ offs, int* __restrict__ cursor) {
    __shared__ int chunkbase;
    __shared__ int wsum[4];
    int tid = threadIdx.x, lane = tid & 63, wid = tid >> 6;
    if (tid == 0) { int a = 0; for (int i = 0; i < (int)blockIdx.x; ++i) a += totals[i]; chunkbase = a; }
    int base = blockIdx.x * 1024 + tid * 4;
    int v[4]; int s = 0;
    #pragma unroll
    for (int j = 0; j < 4; ++j) { int i = base + j; v[j] = (i < N_NODES) ? counts[i] + 1 : 0; s += v[j]; }
    int ts = s;
    #pragma unroll
    for (int d = 1; d < 64; d <<= 1) { int t = __shfl_up(ts, d, 64); if (lane >= d) ts += t; }
    if (lane == 63) wsum[wid] = ts;
    __syncthreads();
    int wbase = 0;
    #pragma unroll
    for (int w = 0; w < 4; ++w) if (w < wid) wbase += wsum[w];
    int excl = chunkbase + wbase + (ts - s);
    #pragma unroll
    for (int j = 0; j < 4; ++j) {
        int i = base + j;
        if (i < N_NODES) { offs[i] = excl; cursor[i] = excl; }
        excl += v[j];
        if (i == N_NODES - 1) offs[N_NODES] = excl;
    }
}

// compressed edge record: u16 src | f16 norm << 16
__global__ void fill_csr(const int* __restrict__ src, const int* __restrict__ dst,
                         const float* __restrict__ dinv, int* cursor,
                         unsigned* __restrict__ edges) {
    int e = blockIdx.x * 256 + threadIdx.x;
    if (e < N_EDGES) {
        int s = src[e], d = dst[e];
        int pos = atomicAdd(&cursor[d], 1);
        unsigned short hb = __builtin_bit_cast(unsigned short, __float2half(dinv[s] * dinv[d]));
        edges[pos] = (unsigned)s | ((unsigned)hb << 16);
    }
}

// self edge (weight 1/deg) appended in each row's last slot
__global__ void fill_self(const int* __restrict__ counts, const int* __restrict__ offs,
                          unsigned* __restrict__ edges) {
    int i = blockIdx.x * 256 + threadIdx.x;
    if (i < N_NODES) {
        float w = 1.0f / ((float)counts[i] + 1.0f);
        unsigned short hb = __builtin_bit_cast(unsigned short, __float2half(w));
        edges[offs[i] + counts[i]] = (unsigned)i | ((unsigned)hb << 16);
    }
}

// ---------------- MFMA GEMM: H(bf16, feature-sliced) = bn_relu(X) @ W ----------------
// 16x16x32 bf16 MFMA. A: row=lane%16, k=(lane>>4)*8+i (f32 X loaded, BN-affine, cvt bf16).
// B: col=lane%16, same k enumeration, read from transposed+padded W in LDS.
// D: col=lane&15, row=(lane>>4)*4+reg  [m89 verified].
// Block = 256 thr (4 waves), tile = 64 rows x FO cols; one tile per block.

template<int FI, int FO, bool BN, bool RELU>
__global__ __launch_bounds__(256)
void gemm_mfma(const float* __restrict__ X, const float* __restrict__ W,
               ushortT* __restrict__ Hb, const float* __restrict__ stats_prev,
               const float* __restrict__ g_prev, const float* __restrict__ be_prev) {
    constexpr int KS = FI / 32;       // k-steps
    constexpr int CT = FO / 16;       // 16-col tiles
    constexpr int LDW = FI + 8;       // padded transposed-W row (bf16): 2-way bank alias = free
    __shared__ ushortT Wt[FO * LDW];
    __shared__ float sscale[FI], sshift[FI];
    const int tid = threadIdx.x;
    if constexpr (BN) {
        if (tid < FI) {
            constexpr float invN = 1.0f / (float)N_NODES;
            float m = stats_prev[tid] * invN;
            float var = stats_prev[FI + tid] * invN - m * m;
            float is = rsqrtf(var + BN_EPS) * g_prev[tid];
            sscale[tid] = is;
            sshift[tid] = be_prev[tid] - m * is;
        }
    }
    // stage W transposed: Wt[n][k] (bf16)
    for (int i = tid; i < FI * FO; i += 256) {
        int k = i / FO, n = i % FO;
        Wt[n * LDW + k] = f2bf(W[i]);
    }
    __syncthreads();

    const int wid = tid >> 6, lane = tid & 63;
    const int lm = lane & 15, lg = lane >> 4;
    const int rbase = blockIdx.x * 64 + wid * 16;

    const int arow = rbase + lm;
    const float* xr = X + (size_t)(arow < N_NODES ? arow : 0) * FI;

    fx4 acc[CT] = {};
    #pragma unroll
    for (int ks = 0; ks < KS; ++ks) {
        const int k0 = ks * 32 + lg * 8;
        float xv[8];
        *(float4*)&xv[0] = *(const float4*)&xr[k0];
        *(float4*)&xv[4] = *(const float4*)&xr[k0 + 4];
        if constexpr (BN) {
            float sc[8], sh[8];
            *(float4*)&sc[0] = *(const float4*)&sscale[k0];
            *(float4*)&sc[4] = *(const float4*)&sscale[k0 + 4];
            *(float4*)&sh[0] = *(const float4*)&sshift[k0];
            *(float4*)&sh[4] = *(const float4*)&sshift[k0 + 4];
            #pragma unroll
            for (int j = 0; j < 8; ++j) {
                xv[j] = fmaf(xv[j], sc[j], sh[j]);
                if constexpr (RELU) xv[j] = fmaxf(xv[j], 0.f);
            }
        }
        short us[8];
        #pragma unroll
        for (int j = 0; j < 8; ++j) us[j] = (short)f2bf(xv[j]);
        bf16x8 afrag = *(const bf16x8*)us;
        #pragma unroll
        for (int ct = 0; ct < CT; ++ct) {
            bf16x8 bfrag = *(const bf16x8*)&Wt[(ct * 16 + lm) * LDW + k0];
            acc[ct] = __builtin_amdgcn_mfma_f32_16x16x32_bf16(afrag, bfrag, acc[ct], 0, 0, 0);
        }
    }
    // store: D row = rbase + lg*4 + j, col = ct*16 + lm; sliced layout [slab][row][32]
    #pragma unroll
    for (int ct = 0; ct < CT; ++ct) {
        int col = ct * 16 + lm;
        ushortT* hp = Hb + (size_t)(col >> 5) * N_NODES * 32 + (col & 31);
        #pragma unroll
        for (int j = 0; j < 4; ++j) {
            int r = rbase + lg * 4 + j;
            if (r < N_NODES) hp[(size_t)r * 32] = f2bf(acc[ct][j]);
        }
    }
}

// ---------------- sliced aggregation (R8, proven at structural floor) ----------------
// pass p gathers only slab p; within a pass, each b&7 subgroup owns a static row range.
// out-writes non-temporal.

template<int FO>
__global__ __launch_bounds__(256)
void aggregate_sliced(const ushortT* __restrict__ Hb, const int* __restrict__ offs,
                      const unsigned* __restrict__ edges, const float* __restrict__ bias,
                      float* __restrict__ out, float* __restrict__ stats) {
    constexpr int NPASS = FO / 32;          // 4 (FO=128) or 2 (FO=64)
    constexpr int XPP = 8 / NPASS;          // subgroups per pass
    constexpr int RPX = N_NODES / XPP;
    const int b = blockIdx.x;
    const int b7 = b & 7;
    const int pass = b7 / XPP;
    const int rx = b7 % XPP;
    const int o = b >> 3;
    const int NB = gridDim.x >> 3;
    const int r_lo = rx * RPX;
    const int r_hi = r_lo + RPX;
    const int lt = threadIdx.x & 7;
    const int sub = threadIdx.x >> 3;
    const uint2* S2 = (const uint2*)(Hb + (size_t)pass * N_NODES * 32);
    const int f0 = pass * 32 + lt * 4;
    const float4 b4 = *(const float4*)&bias[f0];
    float s[4] = {}, s2[4] = {};
    for (int r = r_lo + o * 32 + sub; r < r_hi; r += NB * 32) {
        float a[4] = { b4.x, b4.y, b4.z, b4.w };
        int e = offs[r], en = offs[r + 1];
        for (; e + 2 <= en; e += 2) {
            uint2 ee = *(const uint2*)&edges[e];
            uint2 v0 = S2[(size_t)(ee.x & 0xffff) * 8 + lt];
            uint2 v1 = S2[(size_t)(ee.y & 0xffff) * 8 + lt];
            float w0 = dec_w(ee.x), w1 = dec_w(ee.y);
            float g0[4], g1[4];
            cvt4(v0, g0); cvt4(v1, g1);
            #pragma unroll
            for (int j = 0; j < 4; ++j) a[j] = fmaf(g0[j], w0, a[j]);
            #pragma unroll
            for (int j = 0; j < 4; ++j) a[j] = fmaf(g1[j], w1, a[j]);
        }
        if (e < en) {
            unsigned ee = edges[e];
            float w = dec_w(ee);
            float g[4];
            cvt4(S2[(size_t)(ee & 0xffff) * 8 + lt], g);
            #pragma unroll
            for (int j = 0; j < 4; ++j) a[j] = fmaf(g[j], w, a[j]);
        }
        fx4 o4 = { a[0], a[1], a[2], a[3] };
        __builtin_nontemporal_store(o4, (fx4*)&out[(size_t)r * FO + f0]);
        #pragma unroll
        for (int j = 0; j < 4; ++j) { s[j] += a[j]; s2[j] += a[j] * a[j]; }
    }
    __shared__ float ls[256][4], ls2[256][4];
    #pragma unroll
    for (int j = 0; j < 4; ++j) { ls[threadIdx.x][j] = s[j]; ls2[threadIdx.x][j] = s2[j]; }
    __syncthreads();
    if (sub == 0) {
        for (int t = 1; t < 32; ++t) {
            #pragma unroll
            for (int j = 0; j < 4; ++j) {
                s[j] += ls[t * 8 + lt][j];
                s2[j] += ls2[t * 8 + lt][j];
            }
        }
        #pragma unroll
        for (int j = 0; j < 4; ++j) {
            atomicAdd(&stats[f0 + j], s[j]);
            atomicAdd(&stats[FO + f0 + j], s2[j]);
        }
    }
}

// ---------------- final BatchNorm normalize (layer 5 only) ----------------

template<int FO, bool RELU>
__global__ __launch_bounds__(256)
void bn_norm(const float* __restrict__ X, const float* __restrict__ stats,
             const float* __restrict__ g, const float* __restrict__ be,
             float* __restrict__ Y) {
    constexpr float invN = 1.0f / (float)N_NODES;
    const int total4 = N_NODES * FO / 4;
    for (int idx = blockIdx.x * 256 + threadIdx.x; idx < total4; idx += gridDim.x * 256) {
        int o4 = (idx * 4) & (FO - 1);
        float4 x = ((const float4*)X)[idx];
        float y[4];
        #pragma unroll
        for (int j = 0; j < 4; ++j) {
            int o = o4 + j;
            float m = stats[o] * invN;
            float v = stats[FO + o] * invN - m * m;
            float istd = rsqrtf(v + BN_EPS);
            float val = ((&x.x)[j] - m) * istd * g[o] + be[o];
            if (RELU) val = fmaxf(val, 0.f);
            y[j] = val;
        }
        ((float4*)Y)[idx] = make_float4(y[0], y[1], y[2], y[3]);
    }
}

// ---------------- driver ----------------

extern "C" void kernel_launch(void* const* d_in, const int* in_sizes, int n_in,
                              void* d_out, int out_size, void* d_ws, size_t ws_size,
                              hipStream_t stream) {
    const float* x  = (const float*)d_in[0];
    const int* ei   = (const int*)d_in[1];
    const int* src  = ei;
    const int* dst  = ei + N_EDGES;

    size_t off = 0;
    auto alloc = [&](size_t bytes) -> void* {
        void* p = (char*)d_ws + off;
        off += (bytes + 255) & ~(size_t)255;
        return p;
    };
    int*      counts = (int*)     alloc((size_t)N_NODES * 4);
    int*      offs   = (int*)     alloc((size_t)(N_NODES + 1) * 4);
    int*      cursor = (int*)     alloc((size_t)N_NODES * 4);
    int*      totals = (int*)     alloc((size_t)NCHUNK * 4);
    float*    dinv   = (float*)   alloc((size_t)N_NODES * 4);
    unsigned* edges  = (unsigned*)alloc((size_t)(N_EDGES + N_NODES) * 4);
    float*    stats  = (float*)   alloc(6 * 256 * 4);
    ushortT*  Hb     = (ushortT*) alloc((size_t)N_NODES * 128 * 2);
    float*    A0     = (float*)   alloc((size_t)N_NODES * 128 * 4);
    float*    A1     = (float*)   alloc((size_t)N_NODES * 128 * 4);

    (void)hipMemsetAsync(counts, 0, (size_t)N_NODES * 4, stream);
    (void)hipMemsetAsync(stats, 0, 6 * 256 * 4, stream);

    count_deg<<<(N_EDGES + 255) / 256, 256, 0, stream>>>(dst, counts);
    finalize_deg<<<(N_NODES + 255) / 256, 256, 0, stream>>>(counts, dinv);
    scan_block_sums<<<NCHUNK, 256, 0, stream>>>(counts, totals);
    scan_write<<<NCHUNK, 256, 0, stream>>>(counts, totals, offs, cursor);
    fill_csr<<<(N_EDGES + 255) / 256, 256, 0, stream>>>(src, dst, dinv, cursor, edges);
    fill_self<<<(N_NODES + 255) / 256, 256, 0, stream>>>(counts, offs, edges);

    const float* W[6]; const float* b[6]; const float* g[6]; const float* be[6];
    for (int j = 0; j < 6; ++j) {
        W[j]  = (const float*)d_in[2 + 4 * j];
        b[j]  = (const float*)d_in[3 + 4 * j];
        g[j]  = (const float*)d_in[4 + 4 * j];
        be[j] = (const float*)d_in[5 + 4 * j];
    }
    float* st[6];
    for (int j = 0; j < 6; ++j) st[j] = stats + j * 256;
    float* dout = (float*)d_out;

    gemm_mfma<128, 128, false, false><<<NTILES, 256, 0, stream>>>(x, W[0], Hb, nullptr, nullptr, nullptr);
    aggregate_sliced<128><<<2048, 256, 0, stream>>>(Hb, offs, edges, b[0], A0, st[0]);

    gemm_mfma<128, 128, true, true><<<NTILES, 256, 0, stream>>>(A0, W[1], Hb, st[0], g[0], be[0]);
    aggregate_sliced<128><<<2048, 256, 0, stream>>>(Hb, offs, edges, b[1], A1, st[1]);

    gemm_mfma<128, 64, true, true><<<NTILES, 256, 0, stream>>>(A1, W[2], Hb, st[1], g[1], be[1]);
    aggregate_sliced<64><<<2048, 256, 0, stream>>>(Hb, offs, edges, b[2], A0, st[2]);

    gemm_mfma<64, 128, true, false><<<NTILES, 256, 0, stream>>>(A0, W[3], Hb, st[2], g[2], be[2]);
    aggregate_sliced<128><<<2048, 256, 0, stream>>>(Hb, offs, edges, b[3], A1, st[3]);

    gemm_mfma<128, 128, true, true><<<NTILES, 256, 0, stream>>>(A1, W[4], Hb, st[3], g[3], be[3]);
    aggregate_sliced<128><<<2048, 256, 0, stream>>>(Hb, offs, edges, b[4], A0, st[4]);

    gemm_mfma<128, 128, true, true><<<NTILES, 256, 0, stream>>>(A0, W[5], Hb, st[4], g[4], be[4]);
    aggregate_sliced<128><<<2048, 256, 0, stream>>>(Hb, offs, edges, b[5], dout, st[5]);
    bn_norm<128, false><<<2048, 256, 0, stream>>>(dout, st[5], g[5], be[5], dout);
}